// Round 9
// baseline (644.470 us; speedup 1.0000x reference)
//
#include <hip/hip_runtime.h>
#include <math.h>

#define D 64
#define R 5
#define BLOCK 256
#define NBLOCKS 512
#define WPB (BLOCK / 64)

typedef __attribute__((ext_vector_type(8))) short short8;
typedef __attribute__((ext_vector_type(4))) float f32x4;

__device__ __forceinline__ unsigned short f2bf(float x) {
    unsigned u = __builtin_bit_cast(unsigned, x);
    u = (u + 0x7FFFu + ((u >> 16) & 1u)) >> 16;   // RNE
    return (unsigned short)u;
}
__device__ __forceinline__ float bf2f(unsigned short h) {
    unsigned u = ((unsigned)h) << 16;
    return __builtin_bit_cast(float, u);
}

struct TileData {           // statically-indexed only (rule #20)
    float vsf[2][8];
    float usf[4][4];
};

__device__ __forceinline__ void gather_tile(int t, int li, int lg, int E,
                                            const float* __restrict__ ufeat,
                                            const float* __restrict__ ifeat,
                                            const int* __restrict__ src,
                                            const int* __restrict__ dst,
                                            TileData& td)
{
    const int e  = t * 16 + li;
    const int es = (e < E) ? e : (E - 1);      // clamp: harmless warm loads
    const int ur = src[es], vr = dst[es];
    const float* __restrict__ vrow = ifeat + (size_t)vr * D;
    const float* __restrict__ urow = ufeat + (size_t)ur * D;
    #pragma unroll
    for (int s = 0; s < 2; ++s) {
        const float4 a = *reinterpret_cast<const float4*>(vrow + s * 32 + lg * 8);
        const float4 b = *reinterpret_cast<const float4*>(vrow + s * 32 + lg * 8 + 4);
        td.vsf[s][0] = a.x; td.vsf[s][1] = a.y; td.vsf[s][2] = a.z; td.vsf[s][3] = a.w;
        td.vsf[s][4] = b.x; td.vsf[s][5] = b.y; td.vsf[s][6] = b.z; td.vsf[s][7] = b.w;
    }
    #pragma unroll
    for (int Mt = 0; Mt < 4; ++Mt) {
        const float4 a = *reinterpret_cast<const float4*>(urow + Mt * 16 + lg * 4);
        td.usf[Mt][0] = a.x; td.usf[Mt][1] = a.y; td.usf[Mt][2] = a.z; td.usf[Mt][3] = a.w;
    }
}

__device__ __forceinline__ void compute_tile(const TileData& td, int t,
                                             int l, int li, int lg, int E,
                                             const short* __restrict__ plds,
                                             float* __restrict__ out)
{
    // split vs into bf16 hi/lo B-fragments
    short8 vhi[2], vlo[2];
    #pragma unroll
    for (int s = 0; s < 2; ++s)
        #pragma unroll
        for (int j = 0; j < 8; ++j) {
            const float x = td.vsf[s][j];
            const unsigned short h = f2bf(x);
            vhi[s][j] = (short)h;
            vlo[s][j] = (short)f2bf(x - bf2f(h));
        }

    float scores[R];
    #pragma unroll
    for (int r = 0; r < R; ++r) {
        f32x4 acc[4] = { {0,0,0,0},{0,0,0,0},{0,0,0,0},{0,0,0,0} };
        #pragma unroll
        for (int s = 0; s < 2; ++s) {
            #pragma unroll
            for (int Mt = 0; Mt < 4; ++Mt) {
                const int fbH = (r * 2 + s) * 4 + Mt;
                const short8 aHi = *reinterpret_cast<const short8*>(&plds[fbH * 512 + l * 8]);
                const short8 aLo = *reinterpret_cast<const short8*>(&plds[(fbH + R * 8) * 512 + l * 8]);
                acc[Mt] = __builtin_amdgcn_mfma_f32_16x16x32_bf16(aHi, vhi[s], acc[Mt], 0, 0, 0);
                acc[Mt] = __builtin_amdgcn_mfma_f32_16x16x32_bf16(aLo, vhi[s], acc[Mt], 0, 0, 0);
                acc[Mt] = __builtin_amdgcn_mfma_f32_16x16x32_bf16(aHi, vlo[s], acc[Mt], 0, 0, 0);
            }
        }
        float part = 0.f;
        #pragma unroll
        for (int Mt = 0; Mt < 4; ++Mt)
            #pragma unroll
            for (int j = 0; j < 4; ++j)
                part = fmaf(acc[Mt][j], td.usf[Mt][j], part);
        part += __shfl_xor(part, 16);
        part += __shfl_xor(part, 32);
        scores[r] = part;
    }

    float m = scores[0];
    #pragma unroll
    for (int r = 1; r < R; ++r) m = fmaxf(m, scores[r]);
    float ssum = 0.f, num = 0.f;
    #pragma unroll
    for (int r = 0; r < R; ++r) {
        const float p = expf(scores[r] - m);
        ssum += p;
        num = fmaf((float)(r + 1), p, num);
    }
    const int e = t * 16 + li;
    if (lg == 0 && e < E) out[e] = num / ssum;
}

// LDS (80KB) caps residency at 2 blocks/CU = 2 waves/SIMD, so up to 256 VGPRs
// are occupancy-FREE. waves_per_eu(2,2) tells the allocator that (default
// heuristic targets 128 and spills instead -- R8: 70MB scratch writes).
__global__ __launch_bounds__(BLOCK)
__attribute__((amdgpu_waves_per_eu(2, 2)))
void bidecoder_mfma(const float* __restrict__ ufeat,
                    const float* __restrict__ ifeat,
                    const float* __restrict__ Ps,
                    const int* __restrict__ src,
                    const int* __restrict__ dst,
                    float* __restrict__ out,
                    int E, int NT, int TPB)
{
    __shared__ short plds[40960];   // 80 KB: bf16 hi/lo P fragments

    const int tid = threadIdx.x;

    // one-time P staging: fp32 -> bf16 hi/lo in fragment-ready layout
    for (int i = tid; i < R * D * D; i += BLOCK) {
        const int r = i >> 12, d = (i >> 6) & 63, f = i & 63;
        const float val = Ps[i];
        const unsigned short hi = f2bf(val);
        const unsigned short lo = f2bf(val - bf2f(hi));
        const int s = f >> 5, g = (f >> 3) & 3, j = f & 7;
        const int Mt = d >> 4;
        const int lane = (d & 15) | (g << 4);
        const int slot = lane * 8 + j;
        const int fbH = (r * 2 + s) * 4 + Mt;
        plds[fbH * 512 + slot]           = (short)hi;
        plds[(fbH + R * 8) * 512 + slot] = (short)lo;
    }
    __syncthreads();

    const int l  = tid & 63;
    const int wv = tid >> 6;
    const int li = l & 15;
    const int lg = l >> 4;

    const int t0 = blockIdx.x * TPB;
    int t1 = t0 + TPB; if (t1 > NT) t1 = NT;

    // software pipeline: gathers for tile t+WPB issued before compute(t)
    TileData A, B;
    int t = t0 + wv;
    if (t < t1) {
        gather_tile(t, li, lg, E, ufeat, ifeat, src, dst, A);
        while (true) {
            int tn = t + WPB;
            gather_tile(tn, li, lg, E, ufeat, ifeat, src, dst, B); // clamped ok
            compute_tile(A, t, l, li, lg, E, plds, out);
            t = tn;
            if (t >= t1) break;
            tn = t + WPB;
            gather_tile(tn, li, lg, E, ufeat, ifeat, src, dst, A);
            compute_tile(B, t, l, li, lg, E, plds, out);
            t = tn;
            if (t >= t1) break;
        }
    }
}

extern "C" void kernel_launch(void* const* d_in, const int* in_sizes, int n_in,
                              void* d_out, int out_size, void* d_ws, size_t ws_size,
                              hipStream_t stream)
{
    const float* ufeat = (const float*)d_in[0];
    const float* ifeat = (const float*)d_in[1];
    const float* Ps    = (const float*)d_in[2];
    const int*   src   = (const int*)d_in[3];
    const int*   dst   = (const int*)d_in[4];
    float*       out   = (float*)d_out;
    const int E   = in_sizes[3];
    const int NT  = (E + 15) / 16;
    const int TPB = (NT + NBLOCKS - 1) / NBLOCKS;
    hipLaunchKernelGGL(bidecoder_mfma, dim3(NBLOCKS), dim3(BLOCK), 0, stream,
                       ufeat, ifeat, Ps, src, dst, out, E, NT, TPB);
}